// Round 1
// baseline (315.884 us; speedup 1.0000x reference)
//
#include <hip/hip_runtime.h>
#include <hip/hip_bf16.h>

#define DHEAD 128
#define NSEQ 4096
#define NBATCH 4
#define QB 64
#define KVB 64
#define NWAVE 4

typedef __attribute__((ext_vector_type(8))) short bf16x8;
typedef __attribute__((ext_vector_type(4))) short bf16x4;
typedef __attribute__((ext_vector_type(4))) float f32x4;

#define K_STRIDE 136   // bf16 elems per K-tile row (64 rows)
#define P_STRIDE 72    // bf16 elems per P row (per-wave 16x64 tile)

__device__ __forceinline__ unsigned short f2bf(float f) {
  return __builtin_bit_cast(unsigned short, __float2bfloat16(f));
}

template <int CTRL>
__device__ __forceinline__ float dpp_rot(float x) {
  int v = __builtin_amdgcn_update_dpp(0, __builtin_bit_cast(int, x), CTRL, 0xF, 0xF, false);
  return __builtin_bit_cast(float, v);
}

// byte offset into vt_lds for element V^T[d][kv] (bf16), with 16B-slot XOR swizzle
__device__ __forceinline__ int vt_byte(int d, int kvbyte) {
  int swz = (((d >> 2) & 7) ^ ((d & 3) << 1)) << 4;
  return d * 128 + (kvbyte ^ swz);
}

__global__ __launch_bounds__(256, 2)
void xattn_kernel(const float* __restrict__ S, const float* __restrict__ G,
                  float* __restrict__ out) {
  const int pass = blockIdx.z;            // 0: Q=S,KV=G ; 1: Q=G,KV=S
  const int b    = blockIdx.y;
  const int qblk = blockIdx.x;
  const float* __restrict__ Qp  = pass ? G : S;
  const float* __restrict__ KVp = pass ? S : G;
  const float* Qb  = Qp  + (size_t)b * NSEQ * DHEAD;
  const float* KVb = KVp + (size_t)b * NSEQ * DHEAD;

  const int tid = threadIdx.x;
  const int w   = tid >> 6;
  const int l   = tid & 63;
  const int lg  = l >> 4;    // lane group 0..3
  const int lc  = l & 15;    // lane-in-group

  __shared__ __align__(16) unsigned short k_lds[KVB * K_STRIDE];
  __shared__ __align__(16) unsigned char  vt_lds[DHEAD * 128];     // V^T, swizzled
  __shared__ __align__(16) unsigned short p_lds[NWAVE][16 * P_STRIDE];

  // fold 1/sqrt(D) and log2(e) into Q so softmax runs in exp2 domain
  const float qscale = 0.08838834764831845f * 1.44269504088896341f;

  // ---- load Q fragments (A-layout: row = lc, k = kc*32 + lg*8 + j) ----
  bf16x8 qf[4];
  {
    const float* qsrc = Qb + (size_t)(qblk * QB + w * 16 + lc) * DHEAD + lg * 8;
    #pragma unroll
    for (int kc = 0; kc < 4; ++kc) {
      float4 v0 = *(const float4*)(qsrc + kc * 32);
      float4 v1 = *(const float4*)(qsrc + kc * 32 + 4);
      bf16x8 q;
      q[0] = (short)f2bf(v0.x * qscale); q[1] = (short)f2bf(v0.y * qscale);
      q[2] = (short)f2bf(v0.z * qscale); q[3] = (short)f2bf(v0.w * qscale);
      q[4] = (short)f2bf(v1.x * qscale); q[5] = (short)f2bf(v1.y * qscale);
      q[6] = (short)f2bf(v1.z * qscale); q[7] = (short)f2bf(v1.w * qscale);
      qf[kc] = q;
    }
  }

  f32x4 oacc[8];
  #pragma unroll
  for (int i = 0; i < 8; ++i) oacc[i] = {0.f, 0.f, 0.f, 0.f};
  float mrow[4] = {-1e30f, -1e30f, -1e30f, -1e30f};
  float lrow[4] = {0.f, 0.f, 0.f, 0.f};

  for (int t = 0; t < NSEQ / KVB; ++t) {
    __syncthreads();   // previous tile fully consumed
    // ---- stage KV tile: bf16 K row-major + swizzled V^T ----
    const float* tp = KVb + (size_t)t * KVB * DHEAD;
    #pragma unroll
    for (int i = 0; i < 4; ++i) {
      int mb = i * 256 + tid;
      int kv = (mb >> 5) * 2;          // even kv row
      int d0 = (mb & 31) * 4;          // 4 d-columns
      float4 a0 = *(const float4*)(tp + (size_t)kv * DHEAD + d0);
      float4 a1 = *(const float4*)(tp + (size_t)(kv + 1) * DHEAD + d0);
      unsigned short c00 = f2bf(a0.x), c01 = f2bf(a0.y), c02 = f2bf(a0.z), c03 = f2bf(a0.w);
      unsigned short c10 = f2bf(a1.x), c11 = f2bf(a1.y), c12 = f2bf(a1.z), c13 = f2bf(a1.w);
      bf16x4 r0 = {(short)c00, (short)c01, (short)c02, (short)c03};
      bf16x4 r1 = {(short)c10, (short)c11, (short)c12, (short)c13};
      *(bf16x4*)&k_lds[kv * K_STRIDE + d0]       = r0;
      *(bf16x4*)&k_lds[(kv + 1) * K_STRIDE + d0] = r1;
      unsigned int p0 = (unsigned)c00 | ((unsigned)c10 << 16);
      unsigned int p1 = (unsigned)c01 | ((unsigned)c11 << 16);
      unsigned int p2 = (unsigned)c02 | ((unsigned)c12 << 16);
      unsigned int p3 = (unsigned)c03 | ((unsigned)c13 << 16);
      *(unsigned int*)(vt_lds + vt_byte(d0 + 0, kv * 2)) = p0;
      *(unsigned int*)(vt_lds + vt_byte(d0 + 1, kv * 2)) = p1;
      *(unsigned int*)(vt_lds + vt_byte(d0 + 2, kv * 2)) = p2;
      *(unsigned int*)(vt_lds + vt_byte(d0 + 3, kv * 2)) = p3;
    }
    __syncthreads();

    // ---- QK^T: sim[16 x 64] in 4 col-chunk fragments ----
    f32x4 sim[4];
    #pragma unroll
    for (int cc = 0; cc < 4; ++cc) {
      f32x4 acc = {0.f, 0.f, 0.f, 0.f};
      #pragma unroll
      for (int kc = 0; kc < 4; ++kc) {
        bf16x8 kfrag = *(const bf16x8*)&k_lds[(cc * 16 + lc) * K_STRIDE + kc * 32 + lg * 8];
        acc = __builtin_amdgcn_mfma_f32_16x16x32_bf16(qf[kc], kfrag, acc, 0, 0, 0);
      }
      sim[cc] = acc;
    }

    // ---- online softmax (exp2 domain); DPP row_ror reduce across 16-lane group ----
    #pragma unroll
    for (int r = 0; r < 4; ++r) {
      float tm = fmaxf(fmaxf(sim[0][r], sim[1][r]), fmaxf(sim[2][r], sim[3][r]));
      tm = fmaxf(tm, dpp_rot<0x121>(tm));
      tm = fmaxf(tm, dpp_rot<0x122>(tm));
      tm = fmaxf(tm, dpp_rot<0x124>(tm));
      tm = fmaxf(tm, dpp_rot<0x128>(tm));
      float mn = fmaxf(mrow[r], tm);
      float alpha = exp2f(mrow[r] - mn);
      mrow[r] = mn;
      float ts = 0.f;
      #pragma unroll
      for (int cc = 0; cc < 4; ++cc) {
        float p = exp2f(sim[cc][r] - mn);
        sim[cc][r] = p;
        ts += p;
      }
      ts += dpp_rot<0x121>(ts);
      ts += dpp_rot<0x122>(ts);
      ts += dpp_rot<0x124>(ts);
      ts += dpp_rot<0x128>(ts);
      lrow[r] = lrow[r] * alpha + ts;
      #pragma unroll
      for (int dc = 0; dc < 8; ++dc) oacc[dc][r] *= alpha;
    }

    // ---- P (D-layout) -> per-wave LDS -> A-layout fragments ----
    unsigned short* pw = p_lds[w];
    #pragma unroll
    for (int cc = 0; cc < 4; ++cc) {
      #pragma unroll
      for (int r = 0; r < 4; ++r)
        pw[(lg * 4 + r) * P_STRIDE + cc * 16 + lc] = f2bf(sim[cc][r]);
    }

    // ---- PV: O += P · V ----
    #pragma unroll
    for (int kc2 = 0; kc2 < 2; ++kc2) {
      bf16x8 pfrag = *(const bf16x8*)&pw[lc * P_STRIDE + kc2 * 32 + lg * 8];
      #pragma unroll
      for (int dc = 0; dc < 8; ++dc) {
        bf16x8 vfrag = *(const bf16x8*)(vt_lds + vt_byte(dc * 16 + lc, (kc2 * 32 + lg * 8) * 2));
        oacc[dc] = __builtin_amdgcn_mfma_f32_16x16x32_bf16(pfrag, vfrag, oacc[dc], 0, 0, 0);
      }
    }
  }

  // ---- epilogue: out += 0.5 * O / l   (atomic: two passes hit same rows) ----
  #pragma unroll
  for (int r = 0; r < 4; ++r) {
    float inv = 0.5f / lrow[r];
    int row = qblk * QB + w * 16 + lg * 4 + r;
    float* op = out + ((size_t)b * NSEQ + row) * DHEAD + lc;
    #pragma unroll
    for (int dc = 0; dc < 8; ++dc)
      atomicAdd(op + dc * 16, oacc[dc][r] * inv);
  }
}

extern "C" void kernel_launch(void* const* d_in, const int* in_sizes, int n_in,
                              void* d_out, int out_size, void* d_ws, size_t ws_size,
                              hipStream_t stream) {
  const float* Sp = (const float*)d_in[0];
  const float* Gp = (const float*)d_in[1];
  float* outp = (float*)d_out;
  hipMemsetAsync(outp, 0, (size_t)out_size * sizeof(float), stream);
  dim3 grid(NSEQ / QB, NBATCH, 2);
  xattn_kernel<<<grid, 256, 0, stream>>>(Sp, Gp, outp);
}